// Round 4
// baseline (344.744 us; speedup 1.0000x reference)
//
#include <hip/hip_runtime.h>
#include <hip/hip_bf16.h>

typedef __hip_bfloat16 bf16;
typedef __attribute__((ext_vector_type(8))) short short8;
typedef __attribute__((ext_vector_type(4))) float floatx4;

#define B_DIM 8192
#define H_DIM 1024
#define KSUM 2048      // fused K: 1024 (x·W) + 1024 (h·U)
#define BM 256
#define BN 256
#define BK 64
#define KT 32          // K-tiles = 2048/64
#define NSLOT 10       // LDS ring: 10 half-tile slots x 16KB = 160KB
#define SLOT_ELEMS 8192  // 128 rows x 64 cols bf16
#define CEX_STRIDE 68  // padded floats/row in C-exchange LDS

union BS { bf16 b; short s; };
__device__ __forceinline__ short cvt1(float f) {
  BS u; u.b = __float2bfloat16(f); return u.s;
}
__device__ __forceinline__ short8 cvt8(float4 lo, float4 hi) {
  short8 r;
  r[0] = cvt1(lo.x); r[1] = cvt1(lo.y); r[2] = cvt1(lo.z); r[3] = cvt1(lo.w);
  r[4] = cvt1(hi.x); r[5] = cvt1(hi.y); r[6] = cvt1(hi.z); r[7] = cvt1(hi.w);
  return r;
}

// async global->LDS, 16B/lane; lds dest = wave-uniform base + lane*16.
// NOTE: offset imm MUST be 0 — nonzero imm mis-addressed (prior-session failure).
__device__ __forceinline__ void async_ld16(const bf16* g, bf16* lds) {
  __builtin_amdgcn_global_load_lds(
      (const __attribute__((address_space(1))) unsigned int*)g,
      (__attribute__((address_space(3))) unsigned int*)lds,
      16, 0, 0);
}

// Fused converter (unchanged).
__global__ __launch_bounds__(256) void cvt_pack(
    const float* __restrict__ x, const float* __restrict__ h,
    const float* __restrict__ W, const float* __restrict__ U,
    bf16* __restrict__ Ac, bf16* __restrict__ Bc) {
  const int blk = blockIdx.x;
  if (blk < 8192) {
    const int idx = blk * 256 + threadIdx.x;   // 2M threads
    const long row = idx >> 8;
    const int k0 = (idx & 255) << 3;
    const float* src = (k0 < 1024) ? (x + row * 1024 + k0)
                                   : (h + row * 1024 + (k0 - 1024));
    const float4 lo = *(const float4*)src;
    const float4 hi = *(const float4*)(src + 4);
    *(short8*)(Ac + row * KSUM + k0) = cvt8(lo, hi);
  } else {
    const int idx = (blk - 8192) * 256 + threadIdx.x;   // 1M threads
    const long r = idx >> 8;
    const int k0 = (idx & 255) << 3;
    const int g = (int)(r & 3);
    const long hh = r >> 2;
    const long base = (long)g * (H_DIM * H_DIM) + hh * H_DIM;
    const float* src = (k0 < 1024) ? (W + base + k0) : (U + base + (k0 - 1024));
    const float4 lo = *(const float4*)src;
    const float4 hi = *(const float4*)(src + 4);
    *(short8*)(Bc + r * KSUM + k0) = cvt8(lo, hi);
  }
}

__device__ __forceinline__ float sigmoidf_(float v) {
  return 1.0f / (1.0f + __expf(-v));
}
__device__ __forceinline__ float tanhf_(float v) {
  return 1.0f - 2.0f / (__expf(2.0f * v) + 1.0f);  // safe at +/-inf
}
__device__ __forceinline__ float getc(const float4& v, int t) {
  return t == 0 ? v.x : t == 1 ? v.y : t == 2 ? v.z : v.w;
}

// GEMM M=8192,N=4096,K=2048 (bf16 MFMA) + fused LSTM epilogue.
// 256x256 tile, 8 waves (2M x 4N), per-wave 128x64 output (acc[8][4]).
// LDS = 10-slot ring of 16KB half-tiles; counted vmcnt(4) once per K-tile.
//
// ROUND-4: faithful m201 8-phase schedule, 24-reads/tile read plan.
// 4 phases per K-tile, decomposed by (M-half rh, k-slice s):
//   ph0: read af0s0(4) + bf_s0(4), stage,  sync, 16 MFMA (rh0 x s0)
//   ph1: read af0s1(4) + bf_s1(4), stage,  sync, 16 MFMA (rh0 x s1)
//   ph2: read af1s0(4)  [bf_s0 cached],    sync, 16 MFMA (rh1 x s0)
//   ph3: read af1s1(4)  [bf_s1 cached], vmcnt,  sync, 16 MFMA (rh1 x s1)
// Reads are issued BEFORE each barrier -> they drain in the barrier-wait
// shadow; lgkmcnt(0) after the barrier is then ~free (this is the overlap
// mechanism the previous two rounds lacked: round-1 read 48/tile, round-3
// had no barrier shadow). sched_barrier(0) after lgkmcnt(0) per rule-18.
// Ring safety: reads use slots (4j..4j+3)%10, in-tile writes (4j+6..4j+9)%10
// — disjoint; vmcnt(4) before ph3's barrier guarantees tile j+1 landed while
// keeping the newest 2 half-tiles in flight (never drains to 0 mid-loop).
__global__ __launch_bounds__(512, 2) void gemm_lstm(
    const bf16* __restrict__ Ac, const bf16* __restrict__ Bc,
    const float* __restrict__ cprev_g, const float* __restrict__ bW,
    const float* __restrict__ bU, float* __restrict__ out) {
  extern __shared__ __align__(16) char smem[];
  bf16* const ring = (bf16*)smem;
  float* const cex = (float*)smem;   // epilogue exchange (reuses ring)

  const int tid  = threadIdx.x;
  const int lane = tid & 63;
  const int wv   = tid >> 6;          // 0..7
  const int wm_idx = wv >> 2;         // 0..1  (M half of block tile)
  const int wn_idx = wv & 3;          // 0..3  (64-col stripe)

  // XCD-aware swizzle: 512 blocks, 8 XCDs, each XCD gets 2 n-tiles x 32 m-tiles
  const int blk  = blockIdx.x;
  const int xcd  = blk & 7;
  const int slot = blk >> 3;          // 0..63
  const int mt   = slot & 31;
  const int nt   = (xcd << 1) | (slot >> 5);
  const long m0 = (long)mt * BM;
  const long n0 = (long)nt * BN;

  // staging lane decomposition: 8 rows x 8 chunks (16B) per wave-instruction
  const int lrow   = lane >> 3;
  const int lchunk = lane & 7;
  const int schunk = lchunk ^ lrow;   // XOR-swizzle via pre-swizzled source
  const bf16* const aRow0 = Ac + (m0 + wv * 8 + lrow) * (long)KSUM + schunk * 8;
  const bf16* const bRow0 = Bc + (n0 + wv * 8 + lrow) * (long)KSUM + schunk * 8;

  const int col16 = lane & 15;
  const int quad  = lane >> 4;
  const int x7    = col16 & 7;
  const int bRowOff = (wn_idx & 1) << 6;   // wave's 64-row offset within B-half

  floatx4 acc[8][4];
#pragma unroll
  for (int i = 0; i < 8; ++i)
#pragma unroll
    for (int jq = 0; jq < 4; ++jq) acc[i][jq] = (floatx4){0.f, 0.f, 0.f, 0.f};

  // half-tile h: tile j2 = h>>2, part c = h&3 (0:Ah0 1:Bh0 2:Ah1 3:Bh1)
#define STAGE_HALF(h_)                                                        \
  {                                                                           \
    const int c_ = (h_) & 3;                                                  \
    const long off_ = ((long)((c_ >> 1) * 128)) * KSUM + (long)(((h_) >> 2) * BK); \
    const bf16* s_ = ((c_ & 1) ? bRow0 : aRow0) + off_;                       \
    bf16* d_ = ring + ((h_) % NSLOT) * SLOT_ELEMS + wv * 512;                 \
    async_ld16(s_, d_);                                                       \
    async_ld16(s_ + 64L * KSUM, d_ + 4096);                                   \
  }

#define STAGE_P(p_)                                                           \
  { const int h_ = 4 * j + (p_) + 6; if (h_ < 4 * KT) STAGE_HALF(h_); }

  // 4 A-frag reads for (M-half rh, k-slice s) into dst[4]
#define RD_A4(dst, rh_, s_)                                                   \
  _Pragma("unroll") for (int fi = 0; fi < 4; ++fi)                            \
    dst[fi] = *(const short8*)&rA[((rh_) * 64 + fi * 16 + col16) * 64 +       \
                                  (((((s_) << 2) + quad) ^ x7) << 3)];

  // 4 B-frag reads for k-slice s into dst[4]
#define RD_B4(dst, s_)                                                        \
  _Pragma("unroll") for (int fj = 0; fj < 4; ++fj)                            \
    dst[fj] = *(const short8*)&rB[(bRowOff + fj * 16 + col16) * 64 +          \
                                  (((((s_) << 2) + quad) ^ x7) << 3)];

  // phase sync: pin reads/stages above, barrier (reads drain in its shadow),
  // then lgkmcnt(0) + rule-18 fence so MFMA can't hoist past it.
#define SYNC()                                                                \
  __builtin_amdgcn_sched_barrier(0);                                          \
  __builtin_amdgcn_s_barrier();                                               \
  asm volatile("s_waitcnt lgkmcnt(0)" ::: "memory");                          \
  __builtin_amdgcn_sched_barrier(0);

  // 16-MFMA burst: acc rows accrow_..accrow_+3 += a_[fi] x b_[fj]
#define MM16(accrow_, a_, b_)                                                 \
  __builtin_amdgcn_s_setprio(1);                                              \
  _Pragma("unroll") for (int fi = 0; fi < 4; ++fi)                            \
    _Pragma("unroll") for (int fj = 0; fj < 4; ++fj)                          \
      acc[(accrow_) + fi][fj] = __builtin_amdgcn_mfma_f32_16x16x32_bf16(      \
          a_[fi], b_[fj], acc[(accrow_) + fi][fj], 0, 0, 0);                  \
  __builtin_amdgcn_s_setprio(0);

  // prologue: stage tile0 (h=0..3) + first half of tile1 (h=4,5); wait until
  // tile0 landed -> 2 half-tiles (4 loads) stay in flight.
#pragma unroll
  for (int h = 0; h < 6; ++h) STAGE_HALF(h);
  asm volatile("s_waitcnt vmcnt(4)" ::: "memory");
  __builtin_amdgcn_s_barrier();

#pragma unroll 1
  for (int j = 0; j < KT; ++j) {
    const bf16* const rA =
        ring + ((4 * j + 2 * wm_idx) % NSLOT) * SLOT_ELEMS;
    const bf16* const rB =
        ring + ((4 * j + 1 + ((wn_idx >> 1) << 1)) % NSLOT) * SLOT_ELEMS;
    short8 af0s0[4], af0s1[4], af1s0[4], af1s1[4], bf_s0[4], bf_s1[4];

    // ---- phase 0: rh0 x s0 ----
    RD_A4(af0s0, 0, 0) RD_B4(bf_s0, 0)
    STAGE_P(0)
    SYNC()
    MM16(0, af0s0, bf_s0)
    __builtin_amdgcn_s_barrier();

    // ---- phase 1: rh0 x s1 ----
    RD_A4(af0s1, 0, 1) RD_B4(bf_s1, 1)
    STAGE_P(1)
    SYNC()
    MM16(0, af0s1, bf_s1)
    __builtin_amdgcn_s_barrier();

    // ---- phase 2: rh1 x s0 (bf_s0 cached) ----
    RD_A4(af1s0, 1, 0)
    STAGE_P(2)
    SYNC()
    MM16(4, af1s0, bf_s0)
    __builtin_amdgcn_s_barrier();

    // ---- phase 3: rh1 x s1 (bf_s1 cached) + per-tile counted vmcnt ----
    RD_A4(af1s1, 1, 1)
    STAGE_P(3)
    __builtin_amdgcn_sched_barrier(0);
    if (j < KT - 2) asm volatile("s_waitcnt vmcnt(4)" ::: "memory");
    else            asm volatile("s_waitcnt vmcnt(0)" ::: "memory");
    SYNC()
    MM16(4, af1s1, bf_s1)
    __builtin_amdgcn_s_barrier();
  }

  // ---- fused LSTM epilogue ----
  // C/D layout: col = lane&15, row = (lane>>4)*4 + reg
  const int rquad = (lane >> 4) << 2;
  const int row16 = lane & 15;        // reader role: local output row
  const int tq    = lane >> 4;        // reader role: h-subgroup 0..3
  const long hglob = ((n0 + (long)(wn_idx << 6)) >> 2) + tq * 4;

  float4 bsum[4];
#pragma unroll
  for (int g = 0; g < 4; ++g) {
    const float4 a = *(const float4*)(bW + g * H_DIM + hglob);
    const float4 b = *(const float4*)(bU + g * H_DIM + hglob);
    bsum[g] = (float4){a.x + b.x, a.y + b.y, a.z + b.z, a.w + b.w};
  }

  float* wx = cex + wv * (16 * CEX_STRIDE);   // wave-private region (34.8KB tot)
  const long BH = (long)B_DIM * H_DIM;

#pragma unroll
  for (int ig = 0; ig < 8; ++ig) {
    // stage this 16-row group's 64 cols into LDS [row16][col64]
#pragma unroll
    for (int jj = 0; jj < 4; ++jj)
#pragma unroll
      for (int r = 0; r < 4; ++r)
        wx[(rquad + r) * CEX_STRIDE + jj * 16 + col16] = acc[ig][jj][r];

    // gather 4 gates per output as float4: col64 = h16*4 + g
    float4 g4[4];
#pragma unroll
    for (int t = 0; t < 4; ++t)
      g4[t] = *(const float4*)&wx[row16 * CEX_STRIDE + (tq * 4 + t) * 4];

    const long mrow = m0 + (long)wm_idx * 128 + ig * 16 + row16;
    const float4 cp4 = *(const float4*)(cprev_g + mrow * H_DIM + hglob);

    float hn[4], cn[4];
#pragma unroll
    for (int t = 0; t < 4; ++t) {
      const float gi = g4[t].x + getc(bsum[0], t);
      const float gf = g4[t].y + getc(bsum[1], t);
      const float go = g4[t].z + getc(bsum[2], t);
      const float gg = g4[t].w + getc(bsum[3], t);
      const float I = sigmoidf_(gi);
      const float F = sigmoidf_(gf);
      const float O = sigmoidf_(go);
      const float G = tanhf_(gg);
      const float cv = F * getc(cp4, t) + I * G;
      hn[t] = O * tanhf_(cv);
      cn[t] = cv;
    }
    const float4 hn4 = {hn[0], hn[1], hn[2], hn[3]};
    const float4 cn4 = {cn[0], cn[1], cn[2], cn[3]};
    const long ob = mrow * H_DIM + hglob;
    *(float4*)(out + ob)          = hn4;  // output 0: h_new
    *(float4*)(out + BH + ob)     = hn4;  // output 1: h_new (tuple dup)
    *(float4*)(out + 2 * BH + ob) = cn4;  // output 2: c_new
  }
}

extern "C" void kernel_launch(void* const* d_in, const int* in_sizes, int n_in,
                              void* d_out, int out_size, void* d_ws, size_t ws_size,
                              hipStream_t stream) {
  const float* x  = (const float*)d_in[0];
  const float* h  = (const float*)d_in[1];
  const float* c  = (const float*)d_in[2];
  const float* W  = (const float*)d_in[3];
  const float* bW = (const float*)d_in[4];
  const float* U  = (const float*)d_in[5];
  const float* bU = (const float*)d_in[6];
  float* out = (float*)d_out;

  bf16* Ac = (bf16*)d_ws;                               // 32 MB
  bf16* Bc = (bf16*)((char*)d_ws + (size_t)33554432);   // 16 MB

  static bool attr_done = false;
  if (!attr_done) {
    hipFuncSetAttribute(reinterpret_cast<const void*>(gemm_lstm),
                        hipFuncAttributeMaxDynamicSharedMemorySize, 163840);
    attr_done = true;
  }

  cvt_pack<<<12288, 256, 0, stream>>>(x, h, W, U, Ac, Bc);
  // 32 m-tiles x 16 n-tiles, XCD-swizzled; 160KB dynamic LDS (half-tile ring)
  gemm_lstm<<<512, 512, 163840, stream>>>(Ac, Bc, c, bW, bU, out);
}

// Round 5
// 336.988 us; speedup vs baseline: 1.0230x; 1.0230x over previous
//
#include <hip/hip_runtime.h>
#include <hip/hip_bf16.h>

typedef __hip_bfloat16 bf16;
typedef __attribute__((ext_vector_type(8))) short short8;
typedef __attribute__((ext_vector_type(4))) short short4v;
typedef __attribute__((ext_vector_type(4))) float floatx4;

#define B_DIM 8192
#define H_DIM 1024
#define KSUM 2048      // fused K: 1024 (x·W) + 1024 (h·U)
#define BM 256
#define BN 256
#define BK 64
#define KT 32          // K-tiles = 2048/64
#define NSLOT 10       // LDS ring: 10 half-tile slots x 16KB = 160KB
#define SLOT_ELEMS 8192  // 128 rows x 64 cols bf16
#define CEX_STRIDE 68  // padded floats/row in C-exchange LDS

union BS { bf16 b; short s; };
__device__ __forceinline__ short cvt1(float f) {
  BS u; u.b = __float2bfloat16(f); return u.s;
}
__device__ __forceinline__ short4v cvt4(float4 v) {
  short4v r;
  r[0] = cvt1(v.x); r[1] = cvt1(v.y); r[2] = cvt1(v.z); r[3] = cvt1(v.w);
  return r;
}

// async global->LDS, 16B/lane; lds dest = wave-uniform base + lane*16.
// NOTE: offset imm MUST be 0 — nonzero imm mis-addressed (prior-session failure).
__device__ __forceinline__ void async_ld16(const bf16* g, bf16* lds) {
  __builtin_amdgcn_global_load_lds(
      (const __attribute__((address_space(1))) unsigned int*)g,
      (__attribute__((address_space(3))) unsigned int*)lds,
      16, 0, 0);
}

// cvt_pack v2: fully-coalesced streaming converter.
// Unit = one float4 (16B load, lane-contiguous) -> one short4 (8B store,
// lane-contiguous). Old version loaded at 32B lane stride (half-utilized
// transactions). Grid-stride over 6,291,456 units:
//   [0, 2M):   x   -> Ac4[r*512 + c]        (r=u>>8, c=u&255)
//   [2M, 4M):  h   -> Ac4[r*512 + 256 + c]
//   [4M, 5M):  W   -> Bc4[(hh*4+g)*512 + c]       (g=w>>18, hh=(w>>8)&1023)
//   [5M, 6M):  U   -> Bc4[(hh*4+g)*512 + 256 + c]
#define NX_UNITS 2097152
#define NW_UNITS 1048576
#define TOT_UNITS 6291456
__global__ __launch_bounds__(256) void cvt_pack(
    const float* __restrict__ x, const float* __restrict__ h,
    const float* __restrict__ W, const float* __restrict__ U,
    bf16* __restrict__ Ac, bf16* __restrict__ Bc) {
  const float4* const x4 = (const float4*)x;
  const float4* const h4 = (const float4*)h;
  const float4* const W4 = (const float4*)W;
  const float4* const U4 = (const float4*)U;
  short4v* const Ac4 = (short4v*)Ac;
  short4v* const Bc4 = (short4v*)Bc;

  const int stride = gridDim.x * 256;
  for (long u = blockIdx.x * 256 + threadIdx.x; u < TOT_UNITS; u += stride) {
    if (u < NX_UNITS) {
      const long r = u >> 8; const int c = (int)(u & 255);
      Ac4[r * 512 + c] = cvt4(x4[u]);
    } else if (u < 2 * NX_UNITS) {
      const long v = u - NX_UNITS;
      const long r = v >> 8; const int c = (int)(v & 255);
      Ac4[r * 512 + 256 + c] = cvt4(h4[v]);
    } else if (u < 2 * NX_UNITS + NW_UNITS) {
      const long w = u - 2 * NX_UNITS;
      const int g = (int)(w >> 18); const long hh = (w >> 8) & 1023;
      const int c = (int)(w & 255);
      Bc4[(hh * 4 + g) * 512 + c] = cvt4(W4[w]);
    } else {
      const long w = u - (2 * NX_UNITS + NW_UNITS);
      const int g = (int)(w >> 18); const long hh = (w >> 8) & 1023;
      const int c = (int)(w & 255);
      Bc4[(hh * 4 + g) * 512 + 256 + c] = cvt4(U4[w]);
    }
  }
}

__device__ __forceinline__ float sigmoidf_(float v) {
  return 1.0f / (1.0f + __expf(-v));
}
__device__ __forceinline__ float tanhf_(float v) {
  return 1.0f - 2.0f / (__expf(2.0f * v) + 1.0f);  // safe at +/-inf
}
__device__ __forceinline__ float getc(const float4& v, int t) {
  return t == 0 ? v.x : t == 1 ? v.y : t == 2 ? v.z : v.w;
}

// GEMM M=8192,N=4096,K=2048 (bf16 MFMA) + fused LSTM epilogue.
// EXACT round-3 structure (best measured: 155.4us, MfmaUtil 38.8) — round-4's
// per-phase double-barrier lockstep regressed at 2 waves/SIMD; reverted.
// 256x256 tile, 8 waves (2M x 4N), per-wave 128x64 output (acc[8][4]).
// LDS = 10-slot ring of 16KB half-tiles; counted vmcnt(4) once per K-tile.
// ONE barrier per K-tile, NO manual lgkmcnt: read-groups issued ahead of the
// MFMA bursts that don't need them; compiler's counted auto-lgkmcnt does
// partial waits (G3/G4 drain under MM1, G5 under MM2, G6 under MM3).
__global__ __launch_bounds__(512, 2) void gemm_lstm(
    const bf16* __restrict__ Ac, const bf16* __restrict__ Bc,
    const float* __restrict__ cprev_g, const float* __restrict__ bW,
    const float* __restrict__ bU, float* __restrict__ out) {
  extern __shared__ __align__(16) char smem[];
  bf16* const ring = (bf16*)smem;
  float* const cex = (float*)smem;   // epilogue exchange (reuses ring)

  const int tid  = threadIdx.x;
  const int lane = tid & 63;
  const int wv   = tid >> 6;          // 0..7
  const int wm_idx = wv >> 2;         // 0..1  (M half of block tile)
  const int wn_idx = wv & 3;          // 0..3  (64-col stripe)

  // XCD-aware swizzle: 512 blocks, 8 XCDs, each XCD gets 2 n-tiles x 32 m-tiles
  const int blk  = blockIdx.x;
  const int xcd  = blk & 7;
  const int slot = blk >> 3;          // 0..63
  const int mt   = slot & 31;
  const int nt   = (xcd << 1) | (slot >> 5);
  const long m0 = (long)mt * BM;
  const long n0 = (long)nt * BN;

  // staging lane decomposition: 8 rows x 8 chunks (16B) per wave-instruction
  const int lrow   = lane >> 3;
  const int lchunk = lane & 7;
  const int schunk = lchunk ^ lrow;   // XOR-swizzle via pre-swizzled source
  const bf16* const aRow0 = Ac + (m0 + wv * 8 + lrow) * (long)KSUM + schunk * 8;
  const bf16* const bRow0 = Bc + (n0 + wv * 8 + lrow) * (long)KSUM + schunk * 8;

  const int col16 = lane & 15;
  const int quad  = lane >> 4;
  const int x7    = col16 & 7;
  const int bRowOff = (wn_idx & 1) << 6;   // wave's 64-row offset within B-half

  floatx4 acc[8][4];
#pragma unroll
  for (int i = 0; i < 8; ++i)
#pragma unroll
    for (int jq = 0; jq < 4; ++jq) acc[i][jq] = (floatx4){0.f, 0.f, 0.f, 0.f};

  // half-tile h: tile j2 = h>>2, part c = h&3 (0:Ah0 1:Bh0 2:Ah1 3:Bh1)
#define STAGE_HALF(h_)                                                        \
  {                                                                           \
    const int c_ = (h_) & 3;                                                  \
    const long off_ = ((long)((c_ >> 1) * 128)) * KSUM + (long)(((h_) >> 2) * BK); \
    const bf16* s_ = ((c_ & 1) ? bRow0 : aRow0) + off_;                       \
    bf16* d_ = ring + ((h_) % NSLOT) * SLOT_ELEMS + wv * 512;                 \
    async_ld16(s_, d_);                                                       \
    async_ld16(s_ + 64L * KSUM, d_ + 4096);                                   \
  }

#define STAGE_P(p_)                                                           \
  { const int h_ = 4 * j + (p_) + 6; if (h_ < 4 * KT) STAGE_HALF(h_); }

  // 4 A-frag reads for (M-half rh, k-slice s) into dst[4]
#define RD_A(dst, rh_, s_)                                                    \
  _Pragma("unroll") for (int fi = 0; fi < 4; ++fi)                            \
    dst[fi] = *(const short8*)&rA[((rh_) * 64 + fi * 16 + col16) * 64 +       \
                                  (((((s_) << 2) + quad) ^ x7) << 3)];

  // 4 B-frag reads for k-slice s into dst[4]
#define RD_B(dst, s_)                                                         \
  _Pragma("unroll") for (int fj = 0; fj < 4; ++fj)                            \
    dst[fj] = *(const short8*)&rB[(bRowOff + fj * 16 + col16) * 64 +          \
                                  (((((s_) << 2) + quad) ^ x7) << 3)];

  // 16-MFMA burst: acc rows accrow_..accrow_+3 += a_[fi] x b_[fj]
#define MM(accrow_, a_, b_)                                                   \
  __builtin_amdgcn_s_setprio(1);                                              \
  _Pragma("unroll") for (int fi = 0; fi < 4; ++fi)                            \
    _Pragma("unroll") for (int fj = 0; fj < 4; ++fj)                          \
      acc[(accrow_) + fi][fj] = __builtin_amdgcn_mfma_f32_16x16x32_bf16(      \
          a_[fi], b_[fj], acc[(accrow_) + fi][fj], 0, 0, 0);                  \
  __builtin_amdgcn_s_setprio(0);

#define FENCE() __builtin_amdgcn_sched_barrier(0)

  // prologue: stage tile0 (h=0..3) + first half of tile1 (h=4,5); wait until
  // tile0 landed -> 2 half-tiles (4 loads) stay in flight.
#pragma unroll
  for (int h = 0; h < 6; ++h) STAGE_HALF(h);
  asm volatile("s_waitcnt vmcnt(4)" ::: "memory");
  __builtin_amdgcn_s_barrier();

#pragma unroll 1
  for (int j = 0; j < KT; ++j) {
    const bf16* const rA =
        ring + ((4 * j + 2 * wm_idx) % NSLOT) * SLOT_ELEMS;
    const bf16* const rB =
        ring + ((4 * j + 1 + ((wn_idx >> 1) << 1)) % NSLOT) * SLOT_ELEMS;
    short8 a0s0[4], a0s1[4], a1s0[4], a1s1[4], b_s0[4], b_s1[4];

    RD_A(a0s0, 0, 0) RD_B(b_s0, 0)      // G1+G2: needed by MM1 (and MM3: b_s0)
    FENCE();
    RD_A(a0s1, 0, 1) RD_B(b_s1, 1)      // G3+G4: drain under MM1
    FENCE();
    STAGE_P(0) STAGE_P(1)               // next-tile prefetch (vmcnt, no lgkm)
    FENCE();
    MM(0, a0s0, b_s0)                   // MM1 (auto-lgkmcnt waits G1+G2 only)
    FENCE();
    RD_A(a1s0, 1, 0)                    // G5: drains under MM2
    FENCE();
    MM(0, a0s1, b_s1)                   // MM2
    FENCE();
    RD_A(a1s1, 1, 1)                    // G6: drains under MM3
    STAGE_P(2) STAGE_P(3)
    FENCE();
    MM(4, a1s0, b_s0)                   // MM3
    MM(4, a1s1, b_s1)                   // MM4
    // end-of-tile: tile j+1 fully landed; newest 2 half-tiles may fly.
    if (j < KT - 2) asm volatile("s_waitcnt vmcnt(4)" ::: "memory");
    else            asm volatile("s_waitcnt vmcnt(0)" ::: "memory");
    __builtin_amdgcn_s_barrier();
  }

  // ---- fused LSTM epilogue ----
  // C/D layout: col = lane&15, row = (lane>>4)*4 + reg
  const int rquad = (lane >> 4) << 2;
  const int row16 = lane & 15;        // reader role: local output row
  const int tq    = lane >> 4;        // reader role: h-subgroup 0..3
  const long hglob = ((n0 + (long)(wn_idx << 6)) >> 2) + tq * 4;

  float4 bsum[4];
#pragma unroll
  for (int g = 0; g < 4; ++g) {
    const float4 a = *(const float4*)(bW + g * H_DIM + hglob);
    const float4 b = *(const float4*)(bU + g * H_DIM + hglob);
    bsum[g] = (float4){a.x + b.x, a.y + b.y, a.z + b.z, a.w + b.w};
  }

  float* wx = cex + wv * (16 * CEX_STRIDE);   // wave-private region (34.8KB tot)
  const long BH = (long)B_DIM * H_DIM;

#pragma unroll
  for (int ig = 0; ig < 8; ++ig) {
    // stage this 16-row group's 64 cols into LDS [row16][col64]
#pragma unroll
    for (int jj = 0; jj < 4; ++jj)
#pragma unroll
      for (int r = 0; r < 4; ++r)
        wx[(rquad + r) * CEX_STRIDE + jj * 16 + col16] = acc[ig][jj][r];

    // gather 4 gates per output as float4: col64 = h16*4 + g
    float4 g4[4];
#pragma unroll
    for (int t = 0; t < 4; ++t)
      g4[t] = *(const float4*)&wx[row16 * CEX_STRIDE + (tq * 4 + t) * 4];

    const long mrow = m0 + (long)wm_idx * 128 + ig * 16 + row16;
    const float4 cp4 = *(const float4*)(cprev_g + mrow * H_DIM + hglob);

    float hn[4], cn[4];
#pragma unroll
    for (int t = 0; t < 4; ++t) {
      const float gi = g4[t].x + getc(bsum[0], t);
      const float gf = g4[t].y + getc(bsum[1], t);
      const float go = g4[t].z + getc(bsum[2], t);
      const float gg = g4[t].w + getc(bsum[3], t);
      const float I = sigmoidf_(gi);
      const float F = sigmoidf_(gf);
      const float O = sigmoidf_(go);
      const float G = tanhf_(gg);
      const float cv = F * getc(cp4, t) + I * G;
      hn[t] = O * tanhf_(cv);
      cn[t] = cv;
    }
    const float4 hn4 = {hn[0], hn[1], hn[2], hn[3]};
    const float4 cn4 = {cn[0], cn[1], cn[2], cn[3]};
    const long ob = mrow * H_DIM + hglob;
    *(float4*)(out + ob)          = hn4;  // output 0: h_new
    *(float4*)(out + BH + ob)     = hn4;  // output 1: h_new (tuple dup)
    *(float4*)(out + 2 * BH + ob) = cn4;  // output 2: c_new
  }
}

extern "C" void kernel_launch(void* const* d_in, const int* in_sizes, int n_in,
                              void* d_out, int out_size, void* d_ws, size_t ws_size,
                              hipStream_t stream) {
  const float* x  = (const float*)d_in[0];
  const float* h  = (const float*)d_in[1];
  const float* c  = (const float*)d_in[2];
  const float* W  = (const float*)d_in[3];
  const float* bW = (const float*)d_in[4];
  const float* U  = (const float*)d_in[5];
  const float* bU = (const float*)d_in[6];
  float* out = (float*)d_out;

  bf16* Ac = (bf16*)d_ws;                               // 32 MB
  bf16* Bc = (bf16*)((char*)d_ws + (size_t)33554432);   // 16 MB

  static bool attr_done = false;
  if (!attr_done) {
    hipFuncSetAttribute(reinterpret_cast<const void*>(gemm_lstm),
                        hipFuncAttributeMaxDynamicSharedMemorySize, 163840);
    attr_done = true;
  }

  cvt_pack<<<4096, 256, 0, stream>>>(x, h, W, U, Ac, Bc);
  // 32 m-tiles x 16 n-tiles, XCD-swizzled; 160KB dynamic LDS (half-tile ring)
  gemm_lstm<<<512, 512, 163840, stream>>>(Ac, Bc, c, bW, bU, out);
}